// Round 12
// baseline (652.217 us; speedup 1.0000x reference)
//
#include <hip/hip_runtime.h>
#include <stdint.h>

// WeightOnlyInt8Linear: out[t,o] = sum_k x[t,k] * (int8 w[o,k] * scale[o]) + bias[o]
// M=8192, K=4096, N=11008. x fp32, w int8-as-int32 (harness), out fp32.
// Round 11: break the register-bound occupancy wall. Tile 256x128 (8 waves,
// 4x2, wave tile 64x64) -> acc[4][4] = 64 regs (was 128). Target <=128
// regs/wave => 4 waves/SIMD = 2 INDEPENDENT blocks/CU -> cross-block
// MFMA/LDS overlap (m114). BK=64, triple-buffered LDS (3 x 24 KiB = 72 KiB;
// 2 blocks = 144 <= 160 KiB). Triple buffer => stage(t+2) hits the buffer
// last read at t-1 (>=1 barrier back) -> WAR-safe single-segment slabs:
//   [rd 8 b128; stage(t+2) 3 gloads; lgkm0; 16 MFMA(setprio); VMW(3); bar]
// Paired-row 8-slot XOR swizzle (r9/r10-proven, 0 conflicts).
// int8 MFMA 16x16x64, per-token x quant, bijective XCD swizzle.

#define TOKENS 8192
#define IN_F   4096
#define OUT_F  11008

#define BM 256
#define BN 128
#define BK 64                // int8 k-slab
#define KT   (IN_F / BK)     // 64
#define MBLK (TOKENS / BM)   // 32
#define NBLK (OUT_F / BN)    // 86
#define NWG  (MBLK * NBLK)   // 2752

static_assert(NWG % 8 == 0, "XCD swizzle requires nwg % 8 == 0");

#define LDS_BUF   24576      // A region 16K @0 | B region 8K @16384
#define LDS_TOTAL 73728      // 3 buffers

typedef __attribute__((ext_vector_type(4))) float f32x4;
typedef __attribute__((ext_vector_type(4))) int   i32x4;

__device__ __forceinline__ void gload_lds16(const void* g, void* l) {
  typedef const __attribute__((address_space(1))) unsigned int* gp_t;
  typedef __attribute__((address_space(3))) unsigned int* lp_t;
  __builtin_amdgcn_global_load_lds((gp_t)g, (lp_t)l, 16, 0, 0);
}

#define MFMA(d, a, b) \
  asm("v_mfma_i32_16x16x64_i8 %0, %1, %2, %0" : "+v"(d) : "v"(a), "v"(b))

#define BARRIER __builtin_amdgcn_s_barrier()
#define LGKM0                                                  \
  do {                                                         \
    asm volatile("s_waitcnt lgkmcnt(0)" ::: "memory");         \
    __builtin_amdgcn_sched_barrier(0);                         \
  } while (0)
#define VMW_(N) asm volatile("s_waitcnt vmcnt(" #N ")" ::: "memory")
#define VMW(N) VMW_(N)
#define PRIO1 __builtin_amdgcn_s_setprio(1)
#define PRIO0 __builtin_amdgcn_s_setprio(0)

// ---------------- quantize x: per-token absmax -> int8 + sx ----------------
__global__ __launch_bounds__(256) void quant_x_kernel(
    const float* __restrict__ x, signed char* __restrict__ xq,
    float* __restrict__ sx) {
  const int row = blockIdx.x;
  const int tid = threadIdx.x;
  const float* xr = x + (size_t)row * IN_F;
  f32x4 v[4];
#pragma unroll
  for (int p = 0; p < 4; ++p) v[p] = ((const f32x4*)xr)[tid + 256 * p];
  float am = 0.f;
#pragma unroll
  for (int p = 0; p < 4; ++p)
#pragma unroll
    for (int j = 0; j < 4; ++j) am = fmaxf(am, fabsf(v[p][j]));
#pragma unroll
  for (int off = 32; off; off >>= 1) am = fmaxf(am, __shfl_xor(am, off, 64));
  __shared__ float wmax[4];
  if ((tid & 63) == 0) wmax[tid >> 6] = am;
  __syncthreads();
  am = fmaxf(fmaxf(wmax[0], wmax[1]), fmaxf(wmax[2], wmax[3]));
  const float inv = (am > 0.f) ? 127.0f / am : 0.f;
  if (tid == 0) sx[row] = (am > 0.f) ? am / 127.0f : 1.0f;
  int* xqi = (int*)(xq + (size_t)row * IN_F);
#pragma unroll
  for (int p = 0; p < 4; ++p) {
    int pk = 0;
#pragma unroll
    for (int j = 0; j < 4; ++j) {
      int q = (int)rintf(v[p][j] * inv);   // |x|<=am -> q in [-127,127]
      pk |= (q & 0xff) << (8 * j);
    }
    xqi[tid + 256 * p] = pk;
  }
}

// ---------------- convert w: int32 (values in [-127,127]) -> int8 ----------
__global__ void cvt_w_kernel(const int* __restrict__ w,
                             signed char* __restrict__ wq, int n16) {
  int i = blockIdx.x * blockDim.x + threadIdx.x;
  int stride = gridDim.x * blockDim.x;
  for (int c = i; c < n16; c += stride) {
    const i32x4* src = (const i32x4*)w + (size_t)c * 4;
    i32x4 outv;
#pragma unroll
    for (int q = 0; q < 4; ++q) {
      i32x4 v = src[q];
      outv[q] = (v[0] & 0xff) | ((v[1] & 0xff) << 8) |
                ((v[2] & 0xff) << 16) | (v[3] << 24);
    }
    ((i32x4*)wq)[c] = outv;
  }
}

// ---------------- int8 MFMA GEMM, 256x128, triple-buffered ------------------
// Region layout (A: 256 rows x 64 B = 16 KiB as 128 lines x 128 B;
// B: 128 rows x 64 B = 8 KiB as 64 lines): line L holds rows 2L,2L+1;
// slot s_log = (row&1)*4 + k16chunk, stored at s_phys = s_log ^ (L&7).
// Proven (r9/r10): correct + 0 bank conflicts (16-lane groups hit each
// bank-quad exactly 2x = free minimum for b128).
// Reader: row r = base + m*16 + rsel -> L&7 = rsel>>1 (bases mult. of 16),
// s_phys = ((rsel&1)*4 + grp) ^ (rsel>>1) -> per-thread constant.
__global__ __launch_bounds__(512) void gemm_i8_kernel(
    const signed char* __restrict__ A,   // [TOKENS][IN_F] int8
    const signed char* __restrict__ Bm,  // [OUT_F][IN_F] int8
    const float* __restrict__ sx,        // [TOKENS] per-token x scale
    const float* __restrict__ scale,     // [OUT_F]
    const float* __restrict__ bias,      // [OUT_F]
    float* __restrict__ C)               // [TOKENS][OUT_F] fp32
{
  extern __shared__ char lds[];          // 72 KiB

  const int tid  = threadIdx.x;
  const int lane = tid & 63;
  const int wave = tid >> 6;   // 0..7
  const int wm   = wave >> 1;  // 0..3 (64-row band)
  const int wn   = wave & 1;   // 0..1 (64-col band)
  const int grp  = lane >> 4;  // 0..3 (k 16-chunk)
  const int rsel = lane & 15;  // 0..15

  int bid = blockIdx.x;
  int wg  = (bid & 7) * (NWG / 8) + (bid >> 3);
  const int m_idx = wg % MBLK;
  const int n_idx = wg / MBLK;
  const int row0 = m_idx * BM;
  const int col0 = n_idx * BN;

  // ---- staging: A chunks c=tid, c=tid+512; B chunk c=tid.
  // c -> line L=c>>3, s_phys=c&7, s_log=s_phys^(L&7), row=2L+(s_log>>2),
  // k16 = s_log&3. (c=tid+512: L+64, L&7 same -> row+128, same k16.)
  const int Lc   = tid >> 3;                     // 0..63
  const int slog = (tid & 7) ^ (Lc & 7);
  const int rSt  = 2 * Lc + (slog >> 2);         // 0..127
  const int kSt  = (slog & 3) * 16;
  const signed char* pA0 = A  + (size_t)(row0 + rSt) * IN_F + kSt;
  const signed char* pA1 = pA0 + (size_t)128 * IN_F;
  const signed char* pB0 = Bm + (size_t)(col0 + rSt) * IN_F + kSt;
  const int stBase = wave * 1024;                // wave-uniform

  auto stage = [&](int bo, int t2) {             // 3 gloads/thread
    const int ko = t2 * BK;
    gload_lds16(pA0 + ko, lds + bo + 0     + stBase);
    gload_lds16(pA1 + ko, lds + bo + 8192  + stBase);
    gload_lds16(pB0 + ko, lds + bo + 16384 + stBase);
  };

  // ---- fragment read constants (verified: write/read byte match, e.g.
  // rsel=3,grp=2,m=0 -> byte 240 both sides)
  const int sphysR = ((rsel & 1) * 4 + grp) ^ (rsel >> 1);
  const int fOffC  = (rsel >> 1) * 128 + sphysR * 16;
  const int aOff   = wm * 4096 + fOffC;          // + m*1024
  const int bOff   = 16384 + wn * 4096 + fOffC;  // + n*1024

  i32x4 zero = {0, 0, 0, 0};
  i32x4 acc[4][4];
#pragma unroll
  for (int m = 0; m < 4; ++m)
#pragma unroll
    for (int n = 0; n < 4; ++n) acc[m][n] = zero;

#define DS_A(BO, MI) (*(const i32x4*)(lds + (BO) + aOff + (MI) * 1024))
#define DS_B(BO, NI) (*(const i32x4*)(lds + (BO) + bOff + (NI) * 1024))

  // Segment t (buf BO=t%3): [rd 8; stage(t+2)->(t+2)%3; lgkm0; 16 MFMA;
  // VMW(W); BARRIER]. W=3 steady (retires stage(t+1), needed next segment;
  // stage(t+2)'s 3 stay in flight). Seg62: W=0 (stage(63) must land).
#define SEG(BO, T, STG, BO2, W)                                                \
  {                                                                            \
    i32x4 ar0 = DS_A(BO, 0), ar1 = DS_A(BO, 1);                                \
    i32x4 ar2 = DS_A(BO, 2), ar3 = DS_A(BO, 3);                                \
    i32x4 br0 = DS_B(BO, 0), br1 = DS_B(BO, 1);                                \
    i32x4 br2 = DS_B(BO, 2), br3 = DS_B(BO, 3);                                \
    if (STG) stage((BO2), (T) + 2);                                            \
    LGKM0;                                                                     \
    PRIO1;                                                                     \
    MFMA(acc[0][0], ar0, br0); MFMA(acc[0][1], ar0, br1);                      \
    MFMA(acc[0][2], ar0, br2); MFMA(acc[0][3], ar0, br3);                      \
    MFMA(acc[1][0], ar1, br0); MFMA(acc[1][1], ar1, br1);                      \
    MFMA(acc[1][2], ar1, br2); MFMA(acc[1][3], ar1, br3);                      \
    MFMA(acc[2][0], ar2, br0); MFMA(acc[2][1], ar2, br1);                      \
    MFMA(acc[2][2], ar2, br2); MFMA(acc[2][3], ar2, br3);                      \
    MFMA(acc[3][0], ar3, br0); MFMA(acc[3][1], ar3, br1);                      \
    MFMA(acc[3][2], ar3, br2); MFMA(acc[3][3], ar3, br3);                      \
    PRIO0;                                                                     \
    VMW(W);                                                                    \
    BARRIER;                                                                   \
  }

  // Prologue: stage(0)->buf0, stage(1)->buf1; VMW(3) retires stage(0); bar.
  stage(0, 0);
  stage(LDS_BUF, 1);
  VMW(3);
  BARRIER;

  // KT=64 segments; stage while t+2 <= 63 (t <= 61).
  for (int t = 0; t < 60; t += 3) {
    SEG(0,           t,     1, 2 * LDS_BUF, 3);
    SEG(LDS_BUF,     t + 1, 1, 0,           3);
    SEG(2 * LDS_BUF, t + 2, 1, LDS_BUF,     3);
  }
  SEG(0,           60, 1, 2 * LDS_BUF, 3);
  SEG(LDS_BUF,     61, 1, 0,           3);
  SEG(2 * LDS_BUF, 62, 0, 0,           0);
  SEG(0,           63, 0, 0,           0);

#undef SEG
#undef DS_A
#undef DS_B

  asm volatile("s_nop 7\n\ts_nop 7" :::);

  // Epilogue: C/D layout col=lane&15, row=(lane>>4)*4+v (dtype-independent).
#pragma unroll
  for (int n = 0; n < 4; ++n) {
    int o = col0 + wn * 64 + n * 16 + rsel;
    float s  = scale[o];
    float bz = bias[o];
#pragma unroll
    for (int m = 0; m < 4; ++m) {
      int tr = row0 + wm * 64 + m * 16 + grp * 4;
      const f32x4 sxv = *(const f32x4*)(sx + tr);
      float* cp = C + (size_t)tr * OUT_F + o;
      i32x4 v = acc[m][n];
      cp[0 * (size_t)OUT_F] = (float)v[0] * (sxv[0] * s) + bz;
      cp[1 * (size_t)OUT_F] = (float)v[1] * (sxv[1] * s) + bz;
      cp[2 * (size_t)OUT_F] = (float)v[2] * (sxv[2] * s) + bz;
      cp[3 * (size_t)OUT_F] = (float)v[3] * (sxv[3] * s) + bz;
    }
  }
}

// ---------------- fallback (only if ws too small): naive fp32 ----------------
__global__ void gemm_naive_kernel(const float* __restrict__ x,
                                  const int* __restrict__ w,
                                  const float* __restrict__ sc,
                                  const float* __restrict__ bs,
                                  float* __restrict__ out) {
  long long idx = (long long)blockIdx.x * blockDim.x + threadIdx.x;
  long long total = (long long)TOKENS * OUT_F;
  if (idx >= total) return;
  int t = (int)(idx / OUT_F);
  int o = (int)(idx % OUT_F);
  const float* xp = x + (size_t)t * IN_F;
  const int* wp = w + (size_t)o * IN_F;
  float acc = 0.f;
  for (int k = 0; k < IN_F; k += 4) {
    i32x4 wv = *(const i32x4*)(wp + k);
    f32x4 xv = *(const f32x4*)(xp + k);
    acc += xv[0] * (float)wv[0] + xv[1] * (float)wv[1]
         + xv[2] * (float)wv[2] + xv[3] * (float)wv[3];
  }
  out[idx] = acc * sc[o] + bs[o];
}

extern "C" void kernel_launch(void* const* d_in, const int* in_sizes, int n_in,
                              void* d_out, int out_size, void* d_ws, size_t ws_size,
                              hipStream_t stream) {
  const float* x  = (const float*)d_in[0];
  const int*   qw = (const int*)d_in[1];     // int8 values materialized as int32
  const float* sc = (const float*)d_in[2];
  const float* bs = (const float*)d_in[3];
  float* out = (float*)d_out;

  const size_t xqBytes = (size_t)TOKENS * IN_F;       // 32 MiB
  const size_t wqBytes = (size_t)OUT_F * IN_F;        // 43 MiB
  const size_t sxBytes = (size_t)TOKENS * sizeof(float);

  if (ws_size >= xqBytes + wqBytes + sxBytes) {
    signed char* xq = (signed char*)d_ws;
    signed char* wq = (signed char*)((char*)d_ws + xqBytes);
    float*       sx = (float*)((char*)d_ws + xqBytes + wqBytes);
    quant_x_kernel<<<TOKENS, 256, 0, stream>>>(x, xq, sx);
    cvt_w_kernel<<<2048, 256, 0, stream>>>(qw, wq, OUT_F * IN_F / 16);
    (void)hipFuncSetAttribute((const void*)gemm_i8_kernel,
                              hipFuncAttributeMaxDynamicSharedMemorySize,
                              LDS_TOTAL);
    gemm_i8_kernel<<<NWG, 512, LDS_TOTAL, stream>>>(xq, wq, sx, sc, bs, out);
  } else {
    long long total = (long long)TOKENS * OUT_F;
    int blocks = (int)((total + 255) / 256);
    gemm_naive_kernel<<<blocks, 256, 0, stream>>>(x, qw, sc, bs, out);
  }
}

// Round 13
// 519.018 us; speedup vs baseline: 1.2566x; 1.2566x over previous
//
#include <hip/hip_runtime.h>
#include <stdint.h>

// WeightOnlyInt8Linear: out[t,o] = sum_k x[t,k] * (int8 w[o,k] * scale[o]) + bias[o]
// M=8192, K=4096, N=11008. x fp32, w int8-as-int32 (harness), out fp32.
// Round 12: r8's PROVEN kernel (434us GEMM, best) with the MFMA swapped to
// v_mfma_i32_32x32x32_i8 (measured 4404 vs 3944 TOPS = +11.7% rate, m55/m16).
// Staging writer, LDS regions, XOR swizzle, 4-phase schedule, vmcnt guards,
// tails: byte-identical to r8. Reader: wave tile 128x64 as 4x2 fragments of
// 32x32, kk=0..3 (K=32 each). Read slot byte = (hi^(l&1))*16 +
// ((kk^((l>>1)&3))<<5)  [= (jw ^ (row&7))*16, jw=kk*2+hi] -- lanes 0-7 cover
// slots 0-7 -> conflict-free. C/D: col=lane&31, row=(reg&3)+8*(reg>>2)+
// 4*(lane>>5) (guide-verified m74/m101, dtype-independent).

#define TOKENS 8192
#define IN_F   4096
#define OUT_F  11008

#define BM 256
#define BN 256
#define BK 128               // int8 k-slab per LDS tile
#define KT   (IN_F / BK)     // 32
#define MBLK (TOKENS / BM)   // 32
#define NBLK (OUT_F / BN)    // 43
#define NWG  (MBLK * NBLK)   // 1376

static_assert(NWG % 8 == 0, "XCD swizzle requires nwg % 8 == 0");
static_assert(KT % 2 == 0, "double-buffer parity");

#define LDS_BUF   65536      // per buffer: AL|AH|BL|BH regions of 16 KiB
#define LDS_TOTAL 131072

typedef __attribute__((ext_vector_type(4)))  float f32x4;
typedef __attribute__((ext_vector_type(4)))  int   i32x4;
typedef __attribute__((ext_vector_type(16))) int   i32x16;

__device__ __forceinline__ void gload_lds16(const void* g, void* l) {
  typedef const __attribute__((address_space(1))) unsigned int* gp_t;
  typedef __attribute__((address_space(3))) unsigned int* lp_t;
  __builtin_amdgcn_global_load_lds((gp_t)g, (lp_t)l, 16, 0, 0);
}

#define MFMA32(d, a, b) \
  asm("v_mfma_i32_32x32x32_i8 %0, %1, %2, %0" : "+v"(d) : "v"(a), "v"(b))

#define BARRIER __builtin_amdgcn_s_barrier()
#define LGKM0                                                  \
  do {                                                         \
    asm volatile("s_waitcnt lgkmcnt(0)" ::: "memory");         \
    __builtin_amdgcn_sched_barrier(0);                         \
  } while (0)
#define VMW_(N) asm volatile("s_waitcnt vmcnt(" #N ")" ::: "memory")
#define VMW(N) VMW_(N)
#define PRIO1 __builtin_amdgcn_s_setprio(1)
#define PRIO0 __builtin_amdgcn_s_setprio(0)

// ---------------- quantize x: per-token absmax -> int8 + sx ----------------
__global__ __launch_bounds__(256) void quant_x_kernel(
    const float* __restrict__ x, signed char* __restrict__ xq,
    float* __restrict__ sx) {
  const int row = blockIdx.x;
  const int tid = threadIdx.x;
  const float* xr = x + (size_t)row * IN_F;
  f32x4 v[4];
#pragma unroll
  for (int p = 0; p < 4; ++p) v[p] = ((const f32x4*)xr)[tid + 256 * p];
  float am = 0.f;
#pragma unroll
  for (int p = 0; p < 4; ++p)
#pragma unroll
    for (int j = 0; j < 4; ++j) am = fmaxf(am, fabsf(v[p][j]));
#pragma unroll
  for (int off = 32; off; off >>= 1) am = fmaxf(am, __shfl_xor(am, off, 64));
  __shared__ float wmax[4];
  if ((tid & 63) == 0) wmax[tid >> 6] = am;
  __syncthreads();
  am = fmaxf(fmaxf(wmax[0], wmax[1]), fmaxf(wmax[2], wmax[3]));
  const float inv = (am > 0.f) ? 127.0f / am : 0.f;
  if (tid == 0) sx[row] = (am > 0.f) ? am / 127.0f : 1.0f;
  int* xqi = (int*)(xq + (size_t)row * IN_F);
#pragma unroll
  for (int p = 0; p < 4; ++p) {
    int pk = 0;
#pragma unroll
    for (int j = 0; j < 4; ++j) {
      int q = (int)rintf(v[p][j] * inv);   // |x|<=am -> q in [-127,127]
      pk |= (q & 0xff) << (8 * j);
    }
    xqi[tid + 256 * p] = pk;
  }
}

// ---------------- convert w: int32 (values in [-127,127]) -> int8 ----------
__global__ void cvt_w_kernel(const int* __restrict__ w,
                             signed char* __restrict__ wq, int n16) {
  int i = blockIdx.x * blockDim.x + threadIdx.x;
  int stride = gridDim.x * blockDim.x;
  for (int c = i; c < n16; c += stride) {
    const i32x4* src = (const i32x4*)w + (size_t)c * 4;
    i32x4 outv;
#pragma unroll
    for (int q = 0; q < 4; ++q) {
      i32x4 v = src[q];
      outv[q] = (v[0] & 0xff) | ((v[1] & 0xff) << 8) |
                ((v[2] & 0xff) << 16) | (v[3] << 24);
    }
    ((i32x4*)wq)[c] = outv;
  }
}

// ---------------- int8 MFMA GEMM, 256x256, 32x32x32, 4-phase ----------------
// Regions per buffer (16 KiB = 128 rows x 128 B, row = one K-slab of 128 i8):
//   AL: A rows {0-63,128-191}; AH: {64-127,192-255};
//   BL: B cols {0-31,64-95,128-159,192-223}; BH: those +32.
// Writer (unchanged from r8): region row rr, phys slot p holds k-chunk
// p ^ (rr&7). Reader fragment (mf,nf,kk): A row = wm*128+mf*32+(l&31)
// -> region row wm*64 + (mf&1)*32 + (l&31) in AL (mf<2) / AH (mf>=2);
// B col = wn*64+nf*32+(l&31) -> region row wn*32+(l&31) in BL/BH.
// k-chunk jw = kk*2 + (l>>5); phys slot = jw ^ (l&7).
__global__ __launch_bounds__(512) void gemm_i8_kernel(
    const signed char* __restrict__ A,   // [TOKENS][IN_F] int8
    const signed char* __restrict__ Bm,  // [OUT_F][IN_F] int8
    const float* __restrict__ sx,        // [TOKENS] per-token x scale
    const float* __restrict__ scale,     // [OUT_F]
    const float* __restrict__ bias,      // [OUT_F]
    float* __restrict__ C)               // [TOKENS][OUT_F] fp32
{
  extern __shared__ char lds[];          // 128 KiB

  const int tid  = threadIdx.x;
  const int lane = tid & 63;
  const int wave = tid >> 6;   // 0..7
  const int wm   = wave >> 2;  // 0..1
  const int wn   = wave & 3;   // 0..3
  const int l31  = lane & 31;
  const int hi   = lane >> 5;  // 0..1

  int bid = blockIdx.x;
  int wg  = (bid & 7) * (NWG / 8) + (bid >> 3);
  const int m_idx = wg % MBLK;
  const int n_idx = wg / MBLK;
  const int row0 = m_idx * BM;
  const int col0 = n_idx * BN;

  // ---- staging (byte-identical to r8): per region 1024 chunks of 16 B;
  // thread covers c = p*512+tid; r = c>>3, j = c&7, src slot j^(r&7).
  const int r0  = tid >> 3;
  const int jg  = (tid & 7) ^ (r0 & 7);
  const int gAL0 = r0;
  const int gAL1 = 128 + r0;
  const int gBL0 = r0 + (r0 & 32);
  const int gBL1 = 128 + r0 + (r0 & 32);
  const signed char* pAL0 = A  + (size_t)(row0 + gAL0) * IN_F + jg * 16;
  const signed char* pAL1 = A  + (size_t)(row0 + gAL1) * IN_F + jg * 16;
  const signed char* pAH0 = pAL0 + (size_t)64 * IN_F;
  const signed char* pAH1 = pAL1 + (size_t)64 * IN_F;
  const signed char* pBL0 = Bm + (size_t)(col0 + gBL0) * IN_F + jg * 16;
  const signed char* pBL1 = Bm + (size_t)(col0 + gBL1) * IN_F + jg * 16;
  const signed char* pBH0 = pBL0 + (size_t)32 * IN_F;
  const signed char* pBH1 = pBL1 + (size_t)32 * IN_F;
  const int stBase = wave * 1024;

  auto stALBL = [&](int bo, int t2) {            // 4 gloads
    const int ko = t2 * BK;
    gload_lds16(pAL0 + ko, lds + bo + 0     + stBase);
    gload_lds16(pAL1 + ko, lds + bo + 8192  + stBase);
    gload_lds16(pBL0 + ko, lds + bo + 32768 + stBase);
    gload_lds16(pBL1 + ko, lds + bo + 40960 + stBase);
  };
  auto stBH = [&](int bo, int t2) {              // 2 gloads
    const int ko = t2 * BK;
    gload_lds16(pBH0 + ko, lds + bo + 49152 + stBase);
    gload_lds16(pBH1 + ko, lds + bo + 57344 + stBase);
  };
  auto stAH = [&](int bo, int t2) {              // 2 gloads
    const int ko = t2 * BK;
    gload_lds16(pAH0 + ko, lds + bo + 16384 + stBase);
    gload_lds16(pAH1 + ko, lds + bo + 24576 + stBase);
  };

  // ---- fragment read constants.
  // slot byte for kk = (jw ^ (l&7))*16, jw = kk*2+hi
  //                  = (hi^(l&1))*16 + ((kk ^ ((l>>1)&3)) << 5)
  const int lowb = (hi ^ (lane & 1)) * 16;
  const int kx   = (lane >> 1) & 3;
  const int swk0 = lowb + ((0 ^ kx) << 5);
  const int swk1 = lowb + ((1 ^ kx) << 5);
  const int swk2 = lowb + ((2 ^ kx) << 5);
  const int swk3 = lowb + ((3 ^ kx) << 5);
  const int aBase = (wm * 64 + l31) * 128;       // + (mf&1)*4096, region AL/AH
  const int bBase = (wn * 32 + l31) * 128;       // region BL/BH

  i32x16 acc[4][2];
#pragma unroll
  for (int m = 0; m < 4; ++m)
#pragma unroll
    for (int n = 0; n < 2; ++n)
#pragma unroll
      for (int j = 0; j < 16; ++j) acc[m][n][j] = 0;

#define DS_AL(BO, MI, SW) (*(const i32x4*)(lds + (BO) + 0     + aBase + (MI)*4096 + (SW)))
#define DS_AH(BO, MI, SW) (*(const i32x4*)(lds + (BO) + 16384 + aBase + (MI)*4096 + (SW)))
#define DS_BL(BO, SW)     (*(const i32x4*)(lds + (BO) + 32768 + bBase + (SW)))
#define DS_BH(BO, SW)     (*(const i32x4*)(lds + (BO) + 49152 + bBase + (SW)))

  // Schedule identical to r8 (reads/stages/guards per phase unchanged):
  //   ph0: rd A-lo(8)+B-lo(4); MM mf01 x nf0; VMW(W0); bar
  //   ph1: rd B-hi(4); st ALBL(t+2); MM mf01 x nf1; VMW(W1); bar
  //   ph2: rd A-hi(8); st BH(t+2);   MM mf23 x nf1; bar
  //   ph3: st AH(t+2);               MM mf23 x nf0; VMW(W3); bar
#define TILE(BO, T, DO_STAGE, W0, W1, W3)                                      \
  {                                                                            \
    i32x4 arLo[8], arHi[8], brLo[4], brHi[4];                                  \
    /* ---- ph0 ---- */                                                        \
    _Pragma("unroll") for (int mf = 0; mf < 2; ++mf) {                         \
      arLo[mf * 4 + 0] = DS_AL(BO, mf, swk0);                                  \
      arLo[mf * 4 + 1] = DS_AL(BO, mf, swk1);                                  \
      arLo[mf * 4 + 2] = DS_AL(BO, mf, swk2);                                  \
      arLo[mf * 4 + 3] = DS_AL(BO, mf, swk3);                                  \
    }                                                                          \
    brLo[0] = DS_BL(BO, swk0); brLo[1] = DS_BL(BO, swk1);                      \
    brLo[2] = DS_BL(BO, swk2); brLo[3] = DS_BL(BO, swk3);                      \
    LGKM0;                                                                     \
    PRIO1;                                                                     \
    _Pragma("unroll") for (int mf = 0; mf < 2; ++mf)                           \
      _Pragma("unroll") for (int kk = 0; kk < 4; ++kk)                         \
        MFMA32(acc[mf][0], arLo[mf * 4 + kk], brLo[kk]);                       \
    PRIO0;                                                                     \
    VMW(W0);                                                                   \
    BARRIER;                                                                   \
    /* ---- ph1 ---- */                                                        \
    brHi[0] = DS_BH(BO, swk0); brHi[1] = DS_BH(BO, swk1);                      \
    brHi[2] = DS_BH(BO, swk2); brHi[3] = DS_BH(BO, swk3);                      \
    if (DO_STAGE) stALBL((BO), (T) + 2);                                       \
    LGKM0;                                                                     \
    PRIO1;                                                                     \
    _Pragma("unroll") for (int mf = 0; mf < 2; ++mf)                           \
      _Pragma("unroll") for (int kk = 0; kk < 4; ++kk)                         \
        MFMA32(acc[mf][1], arLo[mf * 4 + kk], brHi[kk]);                       \
    PRIO0;                                                                     \
    VMW(W1);                                                                   \
    BARRIER;                                                                   \
    /* ---- ph2 ---- */                                                        \
    _Pragma("unroll") for (int mf = 0; mf < 2; ++mf) {                         \
      arHi[mf * 4 + 0] = DS_AH(BO, mf, swk0);                                  \
      arHi[mf * 4 + 1] = DS_AH(BO, mf, swk1);                                  \
      arHi[mf * 4 + 2] = DS_AH(BO, mf, swk2);                                  \
      arHi[mf * 4 + 3] = DS_AH(BO, mf, swk3);                                  \
    }                                                                          \
    if (DO_STAGE) stBH((BO), (T) + 2);                                         \
    LGKM0;                                                                     \
    PRIO1;                                                                     \
    _Pragma("unroll") for (int mf = 0; mf < 2; ++mf)                           \
      _Pragma("unroll") for (int kk = 0; kk < 4; ++kk)                         \
        MFMA32(acc[mf + 2][1], arHi[mf * 4 + kk], brHi[kk]);                   \
    PRIO0;                                                                     \
    BARRIER;                                                                   \
    /* ---- ph3 ---- */                                                        \
    if (DO_STAGE) stAH((BO), (T) + 2);                                         \
    PRIO1;                                                                     \
    _Pragma("unroll") for (int mf = 0; mf < 2; ++mf)                           \
      _Pragma("unroll") for (int kk = 0; kk < 4; ++kk)                         \
        MFMA32(acc[mf + 2][0], arHi[mf * 4 + kk], brLo[kk]);                   \
    PRIO0;                                                                     \
    VMW(W3);                                                                   \
    BARRIER;                                                                   \
  }

  // Prologue: stage slabs 0 and 1 in steady-state issue order (16 loads).
  stALBL(0, 0);
  stBH(0, 0);
  stAH(0, 0);
  stALBL(LDS_BUF, 1);
  stBH(LDS_BUF, 1);
  stAH(LDS_BUF, 1);
  VMW(12);   // oldest 4 (ALBL of slab 0) landed; 12 newer stay in flight
  BARRIER;

  for (int t2 = 0; t2 < KT - 2; t2 += 2) {
    TILE(0,       t2,     true, 10, 12, 12);
    TILE(LDS_BUF, t2 + 1, true, 10, 12, 12);
  }
  TILE(0,       KT - 2, false, 10, 8, 4);
  TILE(LDS_BUF, KT - 1, false, 2, 0, 0);

#undef TILE
#undef DS_AL
#undef DS_AH
#undef DS_BL
#undef DS_BH

  asm volatile("s_nop 7\n\ts_nop 7" :::);

  // Epilogue: 32x32 C/D layout (m74/m101): col = lane&31,
  // row = (reg&3) + 8*(reg>>2) + 4*(lane>>5), reg = q*4+j.
#pragma unroll
  for (int nf = 0; nf < 2; ++nf) {
    int o = col0 + wn * 64 + nf * 32 + l31;
    float s  = scale[o];
    float bz = bias[o];
#pragma unroll
    for (int mf = 0; mf < 4; ++mf) {
      int rbase = row0 + wm * 128 + mf * 32 + 4 * hi;
      i32x16 v = acc[mf][nf];
#pragma unroll
      for (int q = 0; q < 4; ++q) {
        int tr = rbase + q * 8;
        const f32x4 sxv = *(const f32x4*)(sx + tr);
        float* cp = C + (size_t)tr * OUT_F + o;
        cp[0 * (size_t)OUT_F] = (float)v[q * 4 + 0] * (sxv[0] * s) + bz;
        cp[1 * (size_t)OUT_F] = (float)v[q * 4 + 1] * (sxv[1] * s) + bz;
        cp[2 * (size_t)OUT_F] = (float)v[q * 4 + 2] * (sxv[2] * s) + bz;
        cp[3 * (size_t)OUT_F] = (float)v[q * 4 + 3] * (sxv[3] * s) + bz;
      }
    }
  }
}

// ---------------- fallback (only if ws too small): naive fp32 ----------------
__global__ void gemm_naive_kernel(const float* __restrict__ x,
                                  const int* __restrict__ w,
                                  const float* __restrict__ sc,
                                  const float* __restrict__ bs,
                                  float* __restrict__ out) {
  long long idx = (long long)blockIdx.x * blockDim.x + threadIdx.x;
  long long total = (long long)TOKENS * OUT_F;
  if (idx >= total) return;
  int t = (int)(idx / OUT_F);
  int o = (int)(idx % OUT_F);
  const float* xp = x + (size_t)t * IN_F;
  const int* wp = w + (size_t)o * IN_F;
  float acc = 0.f;
  for (int k = 0; k < IN_F; k += 4) {
    i32x4 wv = *(const i32x4*)(wp + k);
    f32x4 xv = *(const f32x4*)(xp + k);
    acc += xv[0] * (float)wv[0] + xv[1] * (float)wv[1]
         + xv[2] * (float)wv[2] + xv[3] * (float)wv[3];
  }
  out[idx] = acc * sc[o] + bs[o];
}

extern "C" void kernel_launch(void* const* d_in, const int* in_sizes, int n_in,
                              void* d_out, int out_size, void* d_ws, size_t ws_size,
                              hipStream_t stream) {
  const float* x  = (const float*)d_in[0];
  const int*   qw = (const int*)d_in[1];     // int8 values materialized as int32
  const float* sc = (const float*)d_in[2];
  const float* bs = (const float*)d_in[3];
  float* out = (float*)d_out;

  const size_t xqBytes = (size_t)TOKENS * IN_F;       // 32 MiB
  const size_t wqBytes = (size_t)OUT_F * IN_F;        // 43 MiB
  const size_t sxBytes = (size_t)TOKENS * sizeof(float);

  if (ws_size >= xqBytes + wqBytes + sxBytes) {
    signed char* xq = (signed char*)d_ws;
    signed char* wq = (signed char*)((char*)d_ws + xqBytes);
    float*       sx = (float*)((char*)d_ws + xqBytes + wqBytes);
    quant_x_kernel<<<TOKENS, 256, 0, stream>>>(x, xq, sx);
    cvt_w_kernel<<<2048, 256, 0, stream>>>(qw, wq, OUT_F * IN_F / 16);
    (void)hipFuncSetAttribute((const void*)gemm_i8_kernel,
                              hipFuncAttributeMaxDynamicSharedMemorySize,
                              LDS_TOTAL);
    gemm_i8_kernel<<<NWG, 512, LDS_TOTAL, stream>>>(xq, wq, sx, sc, bs, out);
  } else {
    long long total = (long long)TOKENS * OUT_F;
    int blocks = (int)((total + 255) / 256);
    gemm_naive_kernel<<<blocks, 256, 0, stream>>>(x, qw, sc, bs, out);
  }
}

// Round 14
// 515.923 us; speedup vs baseline: 1.2642x; 1.0060x over previous
//
#include <hip/hip_runtime.h>
#include <stdint.h>

// WeightOnlyInt8Linear: out[t,o] = sum_k x[t,k] * (int8 w[o,k] * scale[o]) + bias[o]
// M=8192, K=4096, N=11008. x fp32, w int8-as-int32 (harness), out fp32.
// Round 13: r8's PROVEN kernel (434us GEMM, 0 bank conflicts) with the
// read->MFMA serialization removed. r5-r12 placed lgkmcnt(0)+sched_barrier(0)
// BETWEEN the ds_reads and the MFMAs, forcing every wave to drain the CU-wide
// LDS queue (~1150 cyc at ph0) before any MFMA -- the m141 mistake. Now the
// compiler interleaves reads and MFMAs with counted lgkmcnt (m97-verified
// behavior). WAR proof preserved: a free lgkmcnt(0) drain at segment END
// (all reads already consumed) before VMW+barrier; sched_barrier(0) brackets
// each s_barrier so nothing crosses segment boundaries (vmcnt accounting and
// region lifetimes identical to r8).
// int8 MFMA 16x16x64 (exact int32 accum), per-token x quant (absmax/127),
// 256x256 tile, BK=128, 8-slot XOR swizzle, double-buffered 128 KiB LDS,
// bijective XCD swizzle. Guards: steady (10,12,12), tails (10,8,4)/(2,0,0).

#define TOKENS 8192
#define IN_F   4096
#define OUT_F  11008

#define BM 256
#define BN 256
#define BK 128               // int8 k-slab per LDS tile
#define KT   (IN_F / BK)     // 32
#define MBLK (TOKENS / BM)   // 32
#define NBLK (OUT_F / BN)    // 43
#define NWG  (MBLK * NBLK)   // 1376

static_assert(NWG % 8 == 0, "XCD swizzle requires nwg % 8 == 0");
static_assert(KT % 2 == 0, "double-buffer parity");

#define LDS_BUF   65536      // per buffer: AL|AH|BL|BH regions of 16 KiB
#define LDS_TOTAL 131072

typedef __attribute__((ext_vector_type(4))) float f32x4;
typedef __attribute__((ext_vector_type(4))) int   i32x4;

__device__ __forceinline__ void gload_lds16(const void* g, void* l) {
  typedef const __attribute__((address_space(1))) unsigned int* gp_t;
  typedef __attribute__((address_space(3))) unsigned int* lp_t;
  __builtin_amdgcn_global_load_lds((gp_t)g, (lp_t)l, 16, 0, 0);
}

#define MFMA(d, a, b) \
  asm("v_mfma_i32_16x16x64_i8 %0, %1, %2, %0" : "+v"(d) : "v"(a), "v"(b))

#define BARRIER  __builtin_amdgcn_s_barrier()
#define SCHEDBAR __builtin_amdgcn_sched_barrier(0)
#define DRAIN    asm volatile("s_waitcnt lgkmcnt(0)" ::: "memory")
#define VMW_(N)  asm volatile("s_waitcnt vmcnt(" #N ")" ::: "memory")
#define VMW(N)   VMW_(N)
#define PRIO1 __builtin_amdgcn_s_setprio(1)
#define PRIO0 __builtin_amdgcn_s_setprio(0)

// ---------------- quantize x: per-token absmax -> int8 + sx ----------------
__global__ __launch_bounds__(256) void quant_x_kernel(
    const float* __restrict__ x, signed char* __restrict__ xq,
    float* __restrict__ sx) {
  const int row = blockIdx.x;
  const int tid = threadIdx.x;
  const float* xr = x + (size_t)row * IN_F;
  f32x4 v[4];
#pragma unroll
  for (int p = 0; p < 4; ++p) v[p] = ((const f32x4*)xr)[tid + 256 * p];
  float am = 0.f;
#pragma unroll
  for (int p = 0; p < 4; ++p)
#pragma unroll
    for (int j = 0; j < 4; ++j) am = fmaxf(am, fabsf(v[p][j]));
#pragma unroll
  for (int off = 32; off; off >>= 1) am = fmaxf(am, __shfl_xor(am, off, 64));
  __shared__ float wmax[4];
  if ((tid & 63) == 0) wmax[tid >> 6] = am;
  __syncthreads();
  am = fmaxf(fmaxf(wmax[0], wmax[1]), fmaxf(wmax[2], wmax[3]));
  const float inv = (am > 0.f) ? 127.0f / am : 0.f;
  if (tid == 0) sx[row] = (am > 0.f) ? am / 127.0f : 1.0f;
  int* xqi = (int*)(xq + (size_t)row * IN_F);
#pragma unroll
  for (int p = 0; p < 4; ++p) {
    int pk = 0;
#pragma unroll
    for (int j = 0; j < 4; ++j) {
      int q = (int)rintf(v[p][j] * inv);   // |x|<=am -> q in [-127,127]
      pk |= (q & 0xff) << (8 * j);
    }
    xqi[tid + 256 * p] = pk;
  }
}

// ---------------- convert w: int32 (values in [-127,127]) -> int8 ----------
__global__ void cvt_w_kernel(const int* __restrict__ w,
                             signed char* __restrict__ wq, int n16) {
  int i = blockIdx.x * blockDim.x + threadIdx.x;
  int stride = gridDim.x * blockDim.x;
  for (int c = i; c < n16; c += stride) {
    const i32x4* src = (const i32x4*)w + (size_t)c * 4;
    i32x4 outv;
#pragma unroll
    for (int q = 0; q < 4; ++q) {
      i32x4 v = src[q];
      outv[q] = (v[0] & 0xff) | ((v[1] & 0xff) << 8) |
                ((v[2] & 0xff) << 16) | (v[3] << 24);
    }
    ((i32x4*)wq)[c] = outv;
  }
}

// ---------------- int8 MFMA GEMM, 256x256, 4-phase, interleaved -------------
// Regions per buffer (16 KiB = 128 rows x 128 B, row = one K-slab of 128 i8):
//   AL: A rows {0-63,128-191}; AH: {64-127,192-255};
//   BL: B rows {wn*64+0..31};  BH: {wn*64+32..63}.
// Row r slot j holds global chunk j^(r&7) (both-sides involution; 0 conflicts
// measured r4-r11). Fragment chunk jw -> byte (jw^(rsel&7))<<4 = swz0 ^ kk*64.
__global__ __launch_bounds__(512) void gemm_i8_kernel(
    const signed char* __restrict__ A,   // [TOKENS][IN_F] int8
    const signed char* __restrict__ Bm,  // [OUT_F][IN_F] int8
    const float* __restrict__ sx,        // [TOKENS] per-token x scale
    const float* __restrict__ scale,     // [OUT_F]
    const float* __restrict__ bias,      // [OUT_F]
    float* __restrict__ C)               // [TOKENS][OUT_F] fp32
{
  extern __shared__ char lds[];          // 128 KiB

  const int tid  = threadIdx.x;
  const int lane = tid & 63;
  const int wave = tid >> 6;   // 0..7
  const int wm   = wave >> 2;  // 0..1
  const int wn   = wave & 3;   // 0..3
  const int grp  = lane >> 4;  // 0..3
  const int rsel = lane & 15;  // 0..15

  int bid = blockIdx.x;
  int wg  = (bid & 7) * (NWG / 8) + (bid >> 3);
  const int m_idx = wg % MBLK;
  const int n_idx = wg / MBLK;
  const int row0 = m_idx * BM;
  const int col0 = n_idx * BN;

  // staging: per region 1024 chunks of 16 B; thread covers c = p*512+tid.
  const int r0  = tid >> 3;                      // region row (p=0); p=1: +64
  const int jg  = (tid & 7) ^ (r0 & 7);          // pre-swizzled slot
  const int gAL0 = r0;
  const int gAL1 = 128 + r0;
  const int gBL0 = r0 + (r0 & 32);
  const int gBL1 = 128 + r0 + (r0 & 32);
  const signed char* pAL0 = A  + (size_t)(row0 + gAL0) * IN_F + jg * 16;
  const signed char* pAL1 = A  + (size_t)(row0 + gAL1) * IN_F + jg * 16;
  const signed char* pAH0 = pAL0 + (size_t)64 * IN_F;
  const signed char* pAH1 = pAL1 + (size_t)64 * IN_F;
  const signed char* pBL0 = Bm + (size_t)(col0 + gBL0) * IN_F + jg * 16;
  const signed char* pBL1 = Bm + (size_t)(col0 + gBL1) * IN_F + jg * 16;
  const signed char* pBH0 = pBL0 + (size_t)32 * IN_F;
  const signed char* pBH1 = pBL1 + (size_t)32 * IN_F;
  const int stBase = wave * 1024;

  auto stALBL = [&](int bo, int t2) {            // 4 gloads
    const int ko = t2 * BK;
    gload_lds16(pAL0 + ko, lds + bo + 0     + stBase);
    gload_lds16(pAL1 + ko, lds + bo + 8192  + stBase);
    gload_lds16(pBL0 + ko, lds + bo + 32768 + stBase);
    gload_lds16(pBL1 + ko, lds + bo + 40960 + stBase);
  };
  auto stBH = [&](int bo, int t2) {              // 2 gloads
    const int ko = t2 * BK;
    gload_lds16(pBH0 + ko, lds + bo + 49152 + stBase);
    gload_lds16(pBH1 + ko, lds + bo + 57344 + stBase);
  };
  auto stAH = [&](int bo, int t2) {              // 2 gloads
    const int ko = t2 * BK;
    gload_lds16(pAH0 + ko, lds + bo + 16384 + stBase);
    gload_lds16(pAH1 + ko, lds + bo + 24576 + stBase);
  };

  const int swz0  = (grp ^ (rsel & 7)) << 4;
  const int swz1  = swz0 ^ 64;
  const int aBase = wm * 8192 + rsel * 128;
  const int bBase = wn * 4096 + rsel * 128;

  i32x4 zero = {0, 0, 0, 0};
  i32x4 acc[8][4];
#pragma unroll
  for (int m = 0; m < 8; ++m)
#pragma unroll
    for (int n = 0; n < 4; ++n) acc[m][n] = zero;

#define DS_AL(BO, MI, SW) (*(const i32x4*)(lds + (BO) + 0     + aBase + (MI)*2048 + (SW)))
#define DS_AH(BO, MI, SW) (*(const i32x4*)(lds + (BO) + 16384 + aBase + (MI)*2048 + (SW)))
#define DS_BL(BO, NI, SW) (*(const i32x4*)(lds + (BO) + 32768 + bBase + (NI)*2048 + (SW)))
#define DS_BH(BO, NI, SW) (*(const i32x4*)(lds + (BO) + 49152 + bBase + (NI)*2048 + (SW)))

  // Segment = [reads; stage; MFMAs (compiler-interleaved, counted lgkmcnt);
  //            DRAIN (free; pins read-retirement for WAR); VMW; schedbar;
  //            barrier; schedbar]. Stage plan + vmcnt guards = r8 verbatim.
#define ENDSEG_W(W) DRAIN; VMW(W); SCHEDBAR; BARRIER; SCHEDBAR
#define ENDSEG_NW   DRAIN; SCHEDBAR; BARRIER; SCHEDBAR

#define TILE(BO, T, DO_STAGE, W0, W1, W3)                                      \
  {                                                                            \
    i32x4 arLo[8], arHi[8], brLo[4], brHi[4];                                  \
    /* ---- ph0: rd A-lo + B-lo ; Q00 ---- */                                  \
    _Pragma("unroll") for (int m = 0; m < 4; ++m) {                            \
      arLo[m * 2]     = DS_AL(BO, m, swz0);                                    \
      arLo[m * 2 + 1] = DS_AL(BO, m, swz1);                                    \
    }                                                                          \
    _Pragma("unroll") for (int n = 0; n < 2; ++n) {                            \
      brLo[n * 2]     = DS_BL(BO, n, swz0);                                    \
      brLo[n * 2 + 1] = DS_BL(BO, n, swz1);                                    \
    }                                                                          \
    PRIO1;                                                                     \
    _Pragma("unroll") for (int m = 0; m < 4; ++m)                              \
      _Pragma("unroll") for (int n = 0; n < 2; ++n)                            \
        _Pragma("unroll") for (int kk = 0; kk < 2; ++kk)                       \
          MFMA(acc[m][n], arLo[m * 2 + kk], brLo[n * 2 + kk]);                 \
    PRIO0;                                                                     \
    ENDSEG_W(W0);                                                              \
    /* ---- ph1: rd B-hi; stage ALBL(T+2); Q01 ---- */                         \
    _Pragma("unroll") for (int n = 0; n < 2; ++n) {                            \
      brHi[n * 2]     = DS_BH(BO, n, swz0);                                    \
      brHi[n * 2 + 1] = DS_BH(BO, n, swz1);                                    \
    }                                                                          \
    if (DO_STAGE) stALBL((BO), (T) + 2);                                       \
    PRIO1;                                                                     \
    _Pragma("unroll") for (int m = 0; m < 4; ++m)                              \
      _Pragma("unroll") for (int n = 0; n < 2; ++n)                            \
        _Pragma("unroll") for (int kk = 0; kk < 2; ++kk)                       \
          MFMA(acc[m][n + 2], arLo[m * 2 + kk], brHi[n * 2 + kk]);             \
    PRIO0;                                                                     \
    ENDSEG_W(W1);                                                              \
    /* ---- ph2: rd A-hi; stage BH(T+2); Q11 ---- */                           \
    _Pragma("unroll") for (int m = 0; m < 4; ++m) {                            \
      arHi[m * 2]     = DS_AH(BO, m, swz0);                                    \
      arHi[m * 2 + 1] = DS_AH(BO, m, swz1);                                    \
    }                                                                          \
    if (DO_STAGE) stBH((BO), (T) + 2);                                         \
    PRIO1;                                                                     \
    _Pragma("unroll") for (int m = 0; m < 4; ++m)                              \
      _Pragma("unroll") for (int n = 0; n < 2; ++n)                            \
        _Pragma("unroll") for (int kk = 0; kk < 2; ++kk)                       \
          MFMA(acc[m + 4][n + 2], arHi[m * 2 + kk], brHi[n * 2 + kk]);         \
    PRIO0;                                                                     \
    ENDSEG_NW;                                                                 \
    /* ---- ph3: stage AH(T+2); Q10 from held regs ---- */                     \
    if (DO_STAGE) stAH((BO), (T) + 2);                                         \
    PRIO1;                                                                     \
    _Pragma("unroll") for (int m = 0; m < 4; ++m)                              \
      _Pragma("unroll") for (int n = 0; n < 2; ++n)                            \
        _Pragma("unroll") for (int kk = 0; kk < 2; ++kk)                       \
          MFMA(acc[m + 4][n], arHi[m * 2 + kk], brLo[n * 2 + kk]);             \
    PRIO0;                                                                     \
    VMW(W3); SCHEDBAR; BARRIER; SCHEDBAR;                                      \
  }

  // Prologue: stage slabs 0 and 1 in steady-state issue order (16 loads).
  stALBL(0, 0);
  stBH(0, 0);
  stAH(0, 0);
  stALBL(LDS_BUF, 1);
  stBH(LDS_BUF, 1);
  stAH(LDS_BUF, 1);
  VMW(12);   // oldest 4 (ALBL of slab 0) landed; 12 newer stay in flight
  SCHEDBAR; BARRIER; SCHEDBAR;

  for (int t2 = 0; t2 < KT - 2; t2 += 2) {
    TILE(0,       t2,     true, 10, 12, 12);
    TILE(LDS_BUF, t2 + 1, true, 10, 12, 12);
  }
  TILE(0,       KT - 2, false, 10, 8, 4);
  TILE(LDS_BUF, KT - 1, false, 2, 0, 0);

#undef TILE
#undef ENDSEG_W
#undef ENDSEG_NW
#undef DS_AL
#undef DS_AH
#undef DS_BL
#undef DS_BH

  asm volatile("s_nop 7\n\ts_nop 7" :::);

  // Epilogue: C/D layout col=lane&15, row=(lane>>4)*4+v (dtype-independent).
#pragma unroll
  for (int n = 0; n < 4; ++n) {
    int o = col0 + wn * 64 + n * 16 + rsel;
    float s  = scale[o];
    float bz = bias[o];
#pragma unroll
    for (int m = 0; m < 8; ++m) {
      int tr = row0 + wm * 128 + m * 16 + grp * 4;
      const f32x4 sxv = *(const f32x4*)(sx + tr);
      float* cp = C + (size_t)tr * OUT_F + o;
      i32x4 v = acc[m][n];
      cp[0 * (size_t)OUT_F] = (float)v[0] * (sxv[0] * s) + bz;
      cp[1 * (size_t)OUT_F] = (float)v[1] * (sxv[1] * s) + bz;
      cp[2 * (size_t)OUT_F] = (float)v[2] * (sxv[2] * s) + bz;
      cp[3 * (size_t)OUT_F] = (float)v[3] * (sxv[3] * s) + bz;
    }
  }
}

// ---------------- fallback (only if ws too small): naive fp32 ----------------
__global__ void gemm_naive_kernel(const float* __restrict__ x,
                                  const int* __restrict__ w,
                                  const float* __restrict__ sc,
                                  const float* __restrict__ bs,
                                  float* __restrict__ out) {
  long long idx = (long long)blockIdx.x * blockDim.x + threadIdx.x;
  long long total = (long long)TOKENS * OUT_F;
  if (idx >= total) return;
  int t = (int)(idx / OUT_F);
  int o = (int)(idx % OUT_F);
  const float* xp = x + (size_t)t * IN_F;
  const int* wp = w + (size_t)o * IN_F;
  float acc = 0.f;
  for (int k = 0; k < IN_F; k += 4) {
    i32x4 wv = *(const i32x4*)(wp + k);
    f32x4 xv = *(const f32x4*)(xp + k);
    acc += xv[0] * (float)wv[0] + xv[1] * (float)wv[1]
         + xv[2] * (float)wv[2] + xv[3] * (float)wv[3];
  }
  out[idx] = acc * sc[o] + bs[o];
}

extern "C" void kernel_launch(void* const* d_in, const int* in_sizes, int n_in,
                              void* d_out, int out_size, void* d_ws, size_t ws_size,
                              hipStream_t stream) {
  const float* x  = (const float*)d_in[0];
  const int*   qw = (const int*)d_in[1];     // int8 values materialized as int32
  const float* sc = (const float*)d_in[2];
  const float* bs = (const float*)d_in[3];
  float* out = (float*)d_out;

  const size_t xqBytes = (size_t)TOKENS * IN_F;       // 32 MiB
  const size_t wqBytes = (size_t)OUT_F * IN_F;        // 43 MiB
  const size_t sxBytes = (size_t)TOKENS * sizeof(float);

  if (ws_size >= xqBytes + wqBytes + sxBytes) {
    signed char* xq = (signed char*)d_ws;
    signed char* wq = (signed char*)((char*)d_ws + xqBytes);
    float*       sx = (float*)((char*)d_ws + xqBytes + wqBytes);
    quant_x_kernel<<<TOKENS, 256, 0, stream>>>(x, xq, sx);
    cvt_w_kernel<<<2048, 256, 0, stream>>>(qw, wq, OUT_F * IN_F / 16);
    (void)hipFuncSetAttribute((const void*)gemm_i8_kernel,
                              hipFuncAttributeMaxDynamicSharedMemorySize,
                              LDS_TOTAL);
    gemm_i8_kernel<<<NWG, 512, LDS_TOTAL, stream>>>(xq, wq, sx, sc, bs, out);
  } else {
    long long total = (long long)TOKENS * OUT_F;
    int blocks = (int)((total + 255) / 256);
    gemm_naive_kernel<<<blocks, 256, 0, stream>>>(x, qw, sc, bs, out);
  }
}